// Round 1
// baseline (99.895 us; speedup 1.0000x reference)
//
#include <hip/hip_runtime.h>
#include <hip/hip_bf16.h>

typedef __bf16 bf16x8 __attribute__((ext_vector_type(8)));
typedef float  f32x4  __attribute__((ext_vector_type(4)));

static constexpr int E    = 1965;   // J*D + J*3
static constexpr int KF   = 1920;   // J*D
static constexpr int NJ   = 15;
static constexpr int NCLS = 68;
static constexpr int NPAD = 80;     // 5 tiles of 16
static constexpr int NT   = 5;
static constexpr int NS   = 60;     // k-steps of 32

// ws layout:
//   pnf: [NT][NS][64][8] __bf16  = 5*60*64*8*2 = 307200 B
//   pa : [NPAD][45] float        = 14400 B
static constexpr size_t PNF_BYTES = (size_t)NT * NS * 64 * 8 * 2;

// ---------------- kernel 1: normalize W -> bf16 fragments + angle extract ----
__global__ __launch_bounds__(256) void prep_kernel(const float* __restrict__ W,
                                                   __bf16* __restrict__ pnf,
                                                   float* __restrict__ pa) {
    const int n = blockIdx.x;      // 0..79
    const int t = threadIdx.x;     // 0..255
    float v[8];
    float ss = 0.f;
    if (n < NCLS && t < 240) {
        const float* src = W + (size_t)n * E + 8 * t;
        #pragma unroll
        for (int i = 0; i < 8; ++i) { v[i] = src[i]; ss += v[i] * v[i]; }
    } else {
        #pragma unroll
        for (int i = 0; i < 8; ++i) v[i] = 0.f;
    }
    // block reduction of sum of squares
    #pragma unroll
    for (int off = 32; off >= 1; off >>= 1) ss += __shfl_xor(ss, off);
    __shared__ float rbuf[4];
    if ((t & 63) == 0) rbuf[t >> 6] = ss;
    __syncthreads();
    const float total = rbuf[0] + rbuf[1] + rbuf[2] + rbuf[3];
    const float rnorm = 1.f / fmaxf(sqrtf(total), 1e-12f);

    if (t < 240) {
        bf16x8 o;
        #pragma unroll
        for (int i = 0; i < 8; ++i) o[i] = (__bf16)(v[i] * rnorm);
        const int s = t >> 2, g = t & 3;
        const int lane = (n & 15) + 16 * g;
        const size_t off = (((size_t)(n >> 4) * NS + s) * 64 + lane) * 8;
        *(bf16x8*)(pnf + off) = o;
    }
    if (t < 45) {
        pa[n * 45 + t] = (n < NCLS) ? W[(size_t)n * E + KF + t] : 0.f;
    }
}

// ---------------- kernel 2: fused GEMM + norm + angle softmax ----------------
__global__ __launch_bounds__(320) void cos_kernel(const float* __restrict__ emb,
                                                  const __bf16* __restrict__ pnf,
                                                  const float* __restrict__ pa,
                                                  float* __restrict__ out) {
    __shared__ float xa_lds[16][45];
    __shared__ float pa_lds[NPAD][45];
    const int tid = threadIdx.x;
    const int m0  = blockIdx.x * 16;

    // stage angle data
    for (int idx = tid; idx < 16 * 45; idx += 320) {
        const int r = idx / 45, c = idx - r * 45;
        xa_lds[r][c] = emb[(size_t)(m0 + r) * E + KF + c];
    }
    for (int idx = tid; idx < NPAD * 45; idx += 320)
        ((float*)pa_lds)[idx] = pa[idx];
    __syncthreads();

    const int w  = tid >> 6;     // N-tile 0..4
    const int l  = tid & 63;
    const int lr = l & 15;       // A row / B col within tile
    const int lg = l >> 4;       // k-group

    const float*  aptr = emb + (size_t)(m0 + lr) * E + lg * 8;
    const bf16x8* bptr = (const bf16x8*)pnf + (size_t)w * NS * 64 + l;

    f32x4 acc[NJ];
    #pragma unroll
    for (int j = 0; j < NJ; ++j) acc[j] = f32x4{0.f, 0.f, 0.f, 0.f};
    float ssq = 0.f;

    #pragma unroll
    for (int s = 0; s < NS; ++s) {
        float a[8];
        __builtin_memcpy(&a[0], aptr + 32 * s,     16);   // 4B-aligned ok
        __builtin_memcpy(&a[4], aptr + 32 * s + 4, 16);
        const bf16x8 b = bptr[s * 64];
        bf16x8 af;
        #pragma unroll
        for (int i = 0; i < 8; ++i) { af[i] = (__bf16)a[i]; ssq += a[i] * a[i]; }
        acc[s >> 2] = __builtin_amdgcn_mfma_f32_16x16x32_bf16(af, b, acc[s >> 2], 0, 0, 0);
    }

    // full row sum-of-squares: lanes {lr, lr+16, lr+32, lr+48} hold partials of row lr
    ssq += __shfl_xor(ssq, 16);
    ssq += __shfl_xor(ssq, 32);

    const int r0 = lg * 4;       // C/D: row = (lane>>4)*4 + reg, col = lane&15
    float rn[4];
    #pragma unroll
    for (int r = 0; r < 4; ++r) {
        const float s2 = __shfl(ssq, r0 + r);   // lane (r0+r) holds row (r0+r)
        rn[r] = 240.f / fmaxf(sqrtf(s2), 1e-12f);   // 16 * 15 / norm
    }

    const int col = w * 16 + lr;
    float num[4] = {0.f, 0.f, 0.f, 0.f};
    float den[4] = {0.f, 0.f, 0.f, 0.f};
    #pragma unroll
    for (int j = 0; j < NJ; ++j) {
        const float p0 = pa_lds[col][3 * j + 0];
        const float p1 = pa_lds[col][3 * j + 1];
        const float p2 = pa_lds[col][3 * j + 2];
        #pragma unroll
        for (int r = 0; r < 4; ++r) {
            const float d0 = xa_lds[r0 + r][3 * j + 0] - p0;
            const float d1 = xa_lds[r0 + r][3 * j + 1] - p1;
            const float d2 = xa_lds[r0 + r][3 * j + 2] - p2;
            const float dist = sqrtf(d0 * d0 + d1 * d1 + d2 * d2);
            const float e = __expf(dist * 0.005f);   // exponents in [0, ~0.05]
            den[r] += e;
            num[r] += e * acc[j][r];
        }
    }

    if (col < NCLS) {
        #pragma unroll
        for (int r = 0; r < 4; ++r)
            out[(size_t)(m0 + r0 + r) * NCLS + col] = rn[r] * num[r] / den[r];
    }
}

extern "C" void kernel_launch(void* const* d_in, const int* in_sizes, int n_in,
                              void* d_out, int out_size, void* d_ws, size_t ws_size,
                              hipStream_t stream) {
    const float* emb = (const float*)d_in[0];
    const float* W   = (const float*)d_in[1];
    float* out = (float*)d_out;
    __bf16* pnf = (__bf16*)d_ws;
    float*  pa  = (float*)((char*)d_ws + PNF_BYTES);
    const int B = in_sizes[0] / E;           // 16384

    prep_kernel<<<NPAD, 256, 0, stream>>>(W, pnf, pa);
    cos_kernel<<<B / 16, 320, 0, stream>>>(emb, pnf, pa, out);
}

// Round 2
// 97.010 us; speedup vs baseline: 1.0297x; 1.0297x over previous
//
#include <hip/hip_runtime.h>
#include <hip/hip_bf16.h>

typedef __bf16 bf16x8 __attribute__((ext_vector_type(8)));
typedef __bf16 bf16x4 __attribute__((ext_vector_type(4)));
typedef float  f32x4  __attribute__((ext_vector_type(4)));

static constexpr int E    = 1965;   // J*D + J*3
static constexpr int KF   = 1920;   // J*D
static constexpr int NJ   = 15;
static constexpr int NCLS = 68;
static constexpr int NPAD = 80;     // 5 tiles of 16
static constexpr int NT   = 5;
static constexpr int NS   = 60;     // k-steps of 32

static constexpr int CH    = 6;     // k-chunks
static constexpr int CCOL  = 320;   // cols per chunk
static constexpr int CSTEP = 10;    // k-steps per chunk
static constexpr int LDR   = 328;   // LDS row stride (bf16), +8 pad = 16B

// ws layout:
//   pnf: [NT][NS][64][8] __bf16  = 307200 B
//   pa : [NPAD][45] float        = 14400 B
static constexpr size_t PNF_BYTES = (size_t)NT * NS * 64 * 8 * 2;

// ---------------- kernel 1: normalize W -> bf16 fragments + angle extract ----
__global__ __launch_bounds__(256) void prep_kernel(const float* __restrict__ W,
                                                   __bf16* __restrict__ pnf,
                                                   float* __restrict__ pa) {
    const int n = blockIdx.x;      // 0..79
    const int t = threadIdx.x;     // 0..255
    float v[8];
    float ss = 0.f;
    if (n < NCLS && t < 240) {
        const float* src = W + (size_t)n * E + 8 * t;
        #pragma unroll
        for (int i = 0; i < 8; ++i) { v[i] = src[i]; ss += v[i] * v[i]; }
    } else {
        #pragma unroll
        for (int i = 0; i < 8; ++i) v[i] = 0.f;
    }
    #pragma unroll
    for (int off = 32; off >= 1; off >>= 1) ss += __shfl_xor(ss, off);
    __shared__ float rbuf[4];
    if ((t & 63) == 0) rbuf[t >> 6] = ss;
    __syncthreads();
    const float total = rbuf[0] + rbuf[1] + rbuf[2] + rbuf[3];
    const float rnorm = 1.f / fmaxf(sqrtf(total), 1e-12f);

    if (t < 240) {
        bf16x8 o;
        #pragma unroll
        for (int i = 0; i < 8; ++i) o[i] = (__bf16)(v[i] * rnorm);
        const int s = t >> 2, g = t & 3;
        const int lane = (n & 15) + 16 * g;
        const size_t off = (((size_t)(n >> 4) * NS + s) * 64 + lane) * 8;
        *(bf16x8*)(pnf + off) = o;
    }
    if (t < 45) {
        pa[n * 45 + t] = (n < NCLS) ? W[(size_t)n * E + KF + t] : 0.f;
    }
}

// ---------------- kernel 2: fused GEMM + norm + angle softmax ----------------
__global__ __launch_bounds__(320) void cos_kernel(const float* __restrict__ emb,
                                                  const __bf16* __restrict__ pnf,
                                                  const float* __restrict__ pa,
                                                  float* __restrict__ out) {
    __shared__ __bf16 abuf[2][16][LDR];       // 20992 B, double-buffered A tile
    __shared__ float  xa[16][45];
    __shared__ float  pal[NPAD][45];
    __shared__ float  sp[320];
    __shared__ float  srow[16];

    const int tid = threadIdx.x;
    const int m0  = blockIdx.x * 16;

    // stage angle data (read in epilogue; barriers in main loop order it)
    for (int idx = tid; idx < 16 * 45; idx += 320) {
        const int r = idx / 45, c = idx - r * 45;
        xa[r][c] = emb[(size_t)(m0 + r) * E + KF + c];
    }
    for (int idx = tid; idx < NPAD * 45; idx += 320)
        ((float*)pal)[idx] = pa[idx];

    // staging role: thread owns row tid/20, segments (tid%20)*4 + 80*i
    const int row = tid / 20;
    const int sc  = tid % 20;
    const float* arow = emb + (size_t)(m0 + row) * E + 4 * sc;

    // compute role
    const int w  = tid >> 6;     // N-tile 0..4
    const int l  = tid & 63;
    const int lr = l & 15;       // A row / B col within tile
    const int lg = l >> 4;       // k-group
    const bf16x8* bptr = (const bf16x8*)pnf + (size_t)w * NS * 64 + l;

    f32x4 acc[NJ];
    #pragma unroll
    for (int j = 0; j < NJ; ++j) acc[j] = f32x4{0.f, 0.f, 0.f, 0.f};
    float ssq = 0.f;

    // prologue: chunk 0 global loads
    float a0[16];
    #pragma unroll
    for (int i = 0; i < 4; ++i)
        __builtin_memcpy(&a0[4 * i], arow + 80 * i, 16);

    #pragma unroll
    for (int c = 0; c < CH; ++c) {
        // pack + write LDS buffer c&1 (regs from previous iteration's loads)
        #pragma unroll
        for (int i = 0; i < 4; ++i) {
            bf16x4 o;
            #pragma unroll
            for (int q = 0; q < 4; ++q) {
                const float x = a0[4 * i + q];
                ssq += x * x;
                o[q] = (__bf16)x;
            }
            *(bf16x4*)&abuf[c & 1][row][4 * sc + 80 * i] = o;
        }
        __syncthreads();   // single barrier per chunk (see hazard analysis)

        // issue next chunk's global loads — overlap with this chunk's MFMA
        if (c + 1 < CH) {
            #pragma unroll
            for (int i = 0; i < 4; ++i)
                __builtin_memcpy(&a0[4 * i], arow + (c + 1) * CCOL + 80 * i, 16);
        }

        // compute chunk c: 10 k-steps
        #pragma unroll
        for (int s = 0; s < CSTEP; ++s) {
            const int gs = c * CSTEP + s;          // static (both loops unrolled)
            const bf16x8 b = bptr[gs * 64];
            const bf16x8 a = *(const bf16x8*)&abuf[c & 1][lr][32 * s + 8 * lg];
            acc[gs >> 2] = __builtin_amdgcn_mfma_f32_16x16x32_bf16(a, b, acc[gs >> 2], 0, 0, 0);
        }
        __syncthreads();
    }

    // row sum-of-squares: thread's ssq covers 96 cols of row tid/20 (fp32 exact)
    sp[tid] = ssq;
    __syncthreads();
    if (tid < 16) {
        float s = 0.f;
        #pragma unroll
        for (int i = 0; i < 20; ++i) s += sp[tid * 20 + i];
        srow[tid] = s;
    }
    __syncthreads();

    const int r0 = lg * 4;       // C/D: row = (lane>>4)*4 + reg, col = lane&15
    float rn[4];
    #pragma unroll
    for (int r = 0; r < 4; ++r)
        rn[r] = 240.f / fmaxf(sqrtf(srow[r0 + r]), 1e-12f);   // 16*15/norm

    const int col = w * 16 + lr;
    float num[4] = {0.f, 0.f, 0.f, 0.f};
    float den[4] = {0.f, 0.f, 0.f, 0.f};
    #pragma unroll
    for (int j = 0; j < NJ; ++j) {
        const float p0 = pal[col][3 * j + 0];
        const float p1 = pal[col][3 * j + 1];
        const float p2 = pal[col][3 * j + 2];
        #pragma unroll
        for (int r = 0; r < 4; ++r) {
            const float d0 = xa[r0 + r][3 * j + 0] - p0;
            const float d1 = xa[r0 + r][3 * j + 1] - p1;
            const float d2 = xa[r0 + r][3 * j + 2] - p2;
            const float dist = sqrtf(d0 * d0 + d1 * d1 + d2 * d2);
            const float e = __expf(dist * 0.005f);   // exponents in [0, ~0.05]
            den[r] += e;
            num[r] += e * acc[j][r];
        }
    }

    if (col < NCLS) {
        #pragma unroll
        for (int r = 0; r < 4; ++r)
            out[(size_t)(m0 + r0 + r) * NCLS + col] = rn[r] * num[r] / den[r];
    }
}

extern "C" void kernel_launch(void* const* d_in, const int* in_sizes, int n_in,
                              void* d_out, int out_size, void* d_ws, size_t ws_size,
                              hipStream_t stream) {
    const float* emb = (const float*)d_in[0];
    const float* W   = (const float*)d_in[1];
    float* out = (float*)d_out;
    __bf16* pnf = (__bf16*)d_ws;
    float*  pa  = (float*)((char*)d_ws + PNF_BYTES);
    const int B = in_sizes[0] / E;           // 16384

    prep_kernel<<<NPAD, 256, 0, stream>>>(W, pnf, pa);
    cos_kernel<<<B / 16, 320, 0, stream>>>(emb, pnf, pa, out);
}

// Round 3
// 72.922 us; speedup vs baseline: 1.3699x; 1.3303x over previous
//
#include <hip/hip_runtime.h>
#include <hip/hip_bf16.h>

typedef __bf16 bf16x8 __attribute__((ext_vector_type(8)));
typedef __bf16 bf16x4 __attribute__((ext_vector_type(4)));
typedef float  f32x4  __attribute__((ext_vector_type(4)));

static constexpr int E    = 1965;   // J*D + J*3
static constexpr int KF   = 1920;   // J*D
static constexpr int NJ   = 15;
static constexpr int NCLS = 68;
static constexpr int NPAD = 80;     // 5 tiles of 16
static constexpr int NT   = 5;
static constexpr int NS   = 60;     // k-steps of 32
static constexpr int AST  = 1928;   // A-tile LDS row stride (bf16): 3856 B, odd/16 -> uniform b128 bank groups

// ws layout:
//   pnf: [NT][NS][64][8] __bf16  = 307200 B
//   pa : [NPAD][45] float        = 14400 B
static constexpr size_t PNF_BYTES = (size_t)NT * NS * 64 * 8 * 2;

// ---------------- kernel 1: normalize W -> bf16 fragments + angle extract ----
__global__ __launch_bounds__(256) void prep_kernel(const float* __restrict__ W,
                                                   __bf16* __restrict__ pnf,
                                                   float* __restrict__ pa) {
    const int n = blockIdx.x;      // 0..79
    const int t = threadIdx.x;     // 0..255
    float v[8];
    float ss = 0.f;
    if (n < NCLS && t < 240) {
        const float* src = W + (size_t)n * E + 8 * t;
        #pragma unroll
        for (int i = 0; i < 8; ++i) { v[i] = src[i]; ss += v[i] * v[i]; }
    } else {
        #pragma unroll
        for (int i = 0; i < 8; ++i) v[i] = 0.f;
    }
    #pragma unroll
    for (int off = 32; off >= 1; off >>= 1) ss += __shfl_xor(ss, off);
    __shared__ float rbuf[4];
    if ((t & 63) == 0) rbuf[t >> 6] = ss;
    __syncthreads();
    const float total = rbuf[0] + rbuf[1] + rbuf[2] + rbuf[3];
    const float rnorm = 1.f / fmaxf(sqrtf(total), 1e-12f);

    if (t < 240) {
        bf16x8 o;
        #pragma unroll
        for (int i = 0; i < 8; ++i) o[i] = (__bf16)(v[i] * rnorm);
        const int s = t >> 2, g = t & 3;
        const int lane = (n & 15) + 16 * g;
        const size_t off = (((size_t)(n >> 4) * NS + s) * 64 + lane) * 8;
        *(bf16x8*)(pnf + off) = o;
    }
    if (t < 45) {
        pa[n * 45 + t] = (n < NCLS) ? W[(size_t)n * E + KF + t] : 0.f;
    }
}

// ---------------- kernel 2: fused GEMM + norm + angle softmax ----------------
__global__ __launch_bounds__(320) void cos_kernel(const float* __restrict__ emb,
                                                  const __bf16* __restrict__ pnf,
                                                  const float* __restrict__ pa,
                                                  float* __restrict__ out) {
    __shared__ __bf16 A[16][AST];          // 61,696 B — whole A tile, single buffer
    __shared__ __bf16 pal[NPAD][52];       //  8,320 B — stride 52: conflict-free b64
    __shared__ float  xa[16][48];          //  3,072 B
    __shared__ float  sp[320];
    __shared__ float  srow[16];

    const int tid = threadIdx.x;
    const int m0  = blockIdx.x * 16;

    // ---- angle staging (ordered by barrier 1) ----
    for (int idx = tid; idx < 16 * 45; idx += 320) {
        const int r = idx / 45, c = idx - r * 45;
        xa[r][c] = emb[(size_t)(m0 + r) * E + KF + c];
    }
    for (int idx = tid; idx < NPAD * 45; idx += 320) {
        const int n = idx / 45, c = idx - n * 45;
        pal[n][c] = (__bf16)pa[idx];
    }

    // ---- A staging: issue ALL 24 dwordx4 loads back-to-back (24-deep MLP) ----
    const int row = tid / 20;
    const int sc  = tid % 20;
    const float* arow = emb + (size_t)(m0 + row) * E + 4 * sc;
    f32x4 av[24];
    #pragma unroll
    for (int i = 0; i < 24; ++i)
        __builtin_memcpy(&av[i], arow + 80 * i, 16);

    float ssq = 0.f;
    #pragma unroll
    for (int i = 0; i < 24; ++i) {
        bf16x4 o;
        #pragma unroll
        for (int q = 0; q < 4; ++q) {
            const float x = av[i][q];
            ssq += x * x;
            o[q] = (__bf16)x;
        }
        *(bf16x4*)&A[row][4 * sc + 80 * i] = o;
    }
    sp[tid] = ssq;
    __syncthreads();                       // barrier 1: A + sp + angles visible

    // ssq reduction hides in the K-loop shadow
    if (tid < 16) {
        float s = 0.f;
        #pragma unroll
        for (int i = 0; i < 20; ++i) s += sp[tid * 20 + i];
        srow[tid] = s;
    }

    // ---- barrier-free K-loop: 60 steps, compiler pipelines freely ----
    const int w  = tid >> 6;     // N-tile 0..4
    const int l  = tid & 63;
    const int lr = l & 15;       // A row / B col within tile
    const int lg = l >> 4;       // k-group
    const bf16x8* bp = (const bf16x8*)pnf + (size_t)w * NS * 64 + l;
    const __bf16* ab = &A[lr][0];

    f32x4 acc[NJ];
    #pragma unroll
    for (int j = 0; j < NJ; ++j) acc[j] = f32x4{0.f, 0.f, 0.f, 0.f};

    #pragma unroll
    for (int s = 0; s < NS; ++s) {
        const bf16x8 b = bp[s * 64];
        const bf16x8 a = *(const bf16x8*)(ab + 32 * s + 8 * lg);
        acc[s >> 2] = __builtin_amdgcn_mfma_f32_16x16x32_bf16(a, b, acc[s >> 2], 0, 0, 0);
    }
    __syncthreads();                       // barrier 2: srow visible

    // ---- epilogue ----
    const int r0  = lg * 4;      // C/D: row = (lane>>4)*4 + reg, col = lane&15
    const int col = w * 16 + lr;

    float rn[4];
    #pragma unroll
    for (int r = 0; r < 4; ++r)
        rn[r] = 240.f / fmaxf(sqrtf(srow[r0 + r]), 1e-12f);   // 16*15/norm

    // hoist pal[col][0..44] into registers (12 x b64 reads, conflict-free)
    float pr[45];
    #pragma unroll
    for (int q = 0; q < 12; ++q) {
        const bf16x4 pv = *(const bf16x4*)&pal[col][4 * q];
        #pragma unroll
        for (int e = 0; e < 4; ++e)
            if (4 * q + e < 45) pr[4 * q + e] = (float)pv[e];
    }

    float num[4] = {0.f, 0.f, 0.f, 0.f};
    float den[4] = {0.f, 0.f, 0.f, 0.f};
    #pragma unroll
    for (int r = 0; r < 4; ++r) {
        f32x4 xr[12];
        #pragma unroll
        for (int q = 0; q < 12; ++q)
            xr[q] = *(const f32x4*)&xa[r0 + r][4 * q];
        #pragma unroll
        for (int j = 0; j < NJ; ++j) {
            const float d0 = xr[(3 * j + 0) >> 2][(3 * j + 0) & 3] - pr[3 * j + 0];
            const float d1 = xr[(3 * j + 1) >> 2][(3 * j + 1) & 3] - pr[3 * j + 1];
            const float d2 = xr[(3 * j + 2) >> 2][(3 * j + 2) & 3] - pr[3 * j + 2];
            const float dist = sqrtf(d0 * d0 + d1 * d1 + d2 * d2);
            const float e = __expf(dist * 0.005f);   // exponents in [0, ~0.05]
            den[r] += e;
            num[r] += e * acc[j][r];
        }
    }

    if (col < NCLS) {
        #pragma unroll
        for (int r = 0; r < 4; ++r)
            out[(size_t)(m0 + r0 + r) * NCLS + col] = rn[r] * num[r] / den[r];
    }
}

extern "C" void kernel_launch(void* const* d_in, const int* in_sizes, int n_in,
                              void* d_out, int out_size, void* d_ws, size_t ws_size,
                              hipStream_t stream) {
    const float* emb = (const float*)d_in[0];
    const float* W   = (const float*)d_in[1];
    float* out = (float*)d_out;
    __bf16* pnf = (__bf16*)d_ws;
    float*  pa  = (float*)((char*)d_ws + PNF_BYTES);
    const int B = in_sizes[0] / E;           // 16384

    prep_kernel<<<NPAD, 256, 0, stream>>>(W, pnf, pa);
    cos_kernel<<<B / 16, 320, 0, stream>>>(emb, pnf, pa, out);
}